// Round 5
// baseline (458.962 us; speedup 1.0000x reference)
//
#include <hip/hip_runtime.h>
#include <hip/hip_bf16.h>
#include <cstdint>

#define HW 256
#define CH 64

typedef __attribute__((ext_vector_type(8))) short bf16x8;
typedef __attribute__((ext_vector_type(4))) float f32x4;

__device__ __forceinline__ float b2f(unsigned short u) {
    union { unsigned int i; float f; } c; c.i = ((unsigned int)u) << 16; return c.f;
}

__device__ __forceinline__ void gload16(const void* g, void* l) {
    __builtin_amdgcn_global_load_lds(
        (const __attribute__((address_space(1))) void*)g,
        (__attribute__((address_space(3))) void*)l, 16, 0, 0);
}

// ---------------------------------------------------------------------------
// Kernel W: conv_w [co][ci][ky][kx] f32 -> wt[ky][kx][co][ci] bf16, with
// 16B-chunk XOR swizzle within each co-row: chunk j stored at j ^ (co&7).
// ---------------------------------------------------------------------------
__global__ void wt_kernel(const float* __restrict__ cw, unsigned short* __restrict__ wt) {
    int i = blockIdx.x * 256 + threadIdx.x;
    if (i >= 9 * 64 * 64) return;
    int e = i & 7, j = (i >> 3) & 7, co = (i >> 6) & 63, t9 = i >> 12;
    int ky = t9 / 3, kx = t9 - ky * 3;
    int ci = j * 8 + e;
    float v = cw[co * 576 + ci * 9 + ky * 3 + kx];
    __hip_bfloat16 h = __float2bfloat16(v);
    wt[t9 * 4096 + co * 64 + ((j ^ (co & 7)) * 8) + e] = *(unsigned short*)&h;
}

// ---------------------------------------------------------------------------
// Kernel A: fused offset conv + tanh + bilinear warp.
// LDS = double-buffered fp32 staging [8ci][20][20] only (26.6KB -> 5 blk/CU).
// Interior blocks stage via global_load_lds w16 (20 floats = 5 chunks, exact).
// Conv: ds_read2_b64 + parity-cndmask, fp32-exact offsets.
// Gather: 4 scalar dword taps/ci straight from global — L2-warm (same tile
// the block just staged), zero LDS, deep MLP.
// grid 2048 (XCD-chunked: each XCD = one batch image).
// Output: warped bf16 NHWC [b][y][x][ci], 16B chunk j stored at j^(x&7).
// ---------------------------------------------------------------------------
__global__ __launch_bounds__(256, 5) void offset_warp_kernel(
    const float* __restrict__ x, const float* __restrict__ ow,
    const float* __restrict__ ob, unsigned short* __restrict__ warped)
{
    __shared__ __align__(16) float sg[2][3328];   // [buf][8*400 + 128 pad]

    const int orig = blockIdx.x;
    const int lid = (orig & 7) * 256 + (orig >> 3);
    const int bx = lid & 15, by = (lid >> 4) & 15, b = lid >> 8;
    const int t = threadIdx.x;
    const int tx = t & 15, ty = t >> 4;
    const int wid = t >> 6;
    const int x0 = bx * 16, y0 = by * 16;
    const int px = x0 + tx, py = y0 + ty;
    const float* xb = x + (size_t)b * CH * HW * HW;
    const bool interior = (bx > 0) && (bx < 15) && (by > 0) && (by < 15);

    auto stage = [&](int g) {
        float* buf = sg[g & 1];
        if (interior) {
            const float* base = xb + (size_t)(g * 8) * (HW * HW) + (y0 - 2) * HW + (x0 - 2);
            #pragma unroll
            for (int k = 0; k < 4; ++k) {
                if (k < 3 || wid == 0) {          // 832 chunks = 13 full waves
                    int c = k * 256 + t;
                    int ci8 = c / 100;
                    int rem = c - ci8 * 100;
                    int ly = rem / 5;
                    int c4 = rem - ly * 5;
                    const float* ga = (c < 800)
                        ? (base + ci8 * (HW * HW) + ly * HW + c4 * 4)
                        : xb;                      // pad chunks: safe dummy src
                    gload16(ga, (char*)buf + k * 4096 + wid * 1024);
                }
            }
        } else {
            for (int k = 0; k < 13; ++k) {
                int i = k * 256 + t;
                if (i < 3200) {
                    int ci8 = i / 400;
                    int rem = i - ci8 * 400;
                    int ly = rem / 20;
                    int lx = rem - ly * 20;
                    int gy = y0 + ly - 2, gx = x0 + lx - 2;
                    float v = 0.f;
                    if ((unsigned)gy < HW && (unsigned)gx < HW)
                        v = xb[(size_t)(g * 8 + ci8) * (HW * HW) + gy * HW + gx];
                    buf[i] = v;
                }
            }
        }
    };

    stage(0);
    asm volatile("s_waitcnt vmcnt(0)" ::: "memory");
    __syncthreads();

    float acc0 = ob[0], acc1 = ob[1];
    const int par = (tx + 1) & 1;
    for (int g = 0; g < 8; ++g) {
        if (g < 7) stage(g + 1);                  // issue next group's DMA early
        const float* buf = sg[g & 1];
        #pragma unroll
        for (int ci8 = 0; ci8 < 8; ++ci8) {
            const int ci = g * 8 + ci8;
            const float* w0 = &ow[ci * 9];        // wave-uniform -> s_load (SMEM pipe)
            const float* w1 = &ow[(CH + ci) * 9];
            const float* q0 = buf + ci8 * 400 + (ty + 1) * 20 + ((tx + 1) & ~1);
            #pragma unroll
            for (int ky = 0; ky < 3; ++ky) {
                const float2 qa = *(const float2*)(q0 + ky * 20);      // merged ->
                const float2 qb = *(const float2*)(q0 + ky * 20 + 2);  // ds_read2_b64
                float t0 = par ? qa.y : qa.x;
                float t1 = par ? qb.x : qa.y;
                float t2 = par ? qb.y : qb.x;
                acc0 = fmaf(t0, w0[ky * 3 + 0], acc0);
                acc1 = fmaf(t0, w1[ky * 3 + 0], acc1);
                acc0 = fmaf(t1, w0[ky * 3 + 1], acc0);
                acc1 = fmaf(t1, w1[ky * 3 + 1], acc1);
                acc0 = fmaf(t2, w0[ky * 3 + 2], acc0);
                acc1 = fmaf(t2, w1[ky * 3 + 2], acc1);
            }
        }
        if (g < 7) {
            asm volatile("s_waitcnt vmcnt(0)" ::: "memory");
            __syncthreads();
        }
    }

    // ---- positions (fp32-exact offsets)
    float off0 = tanhf(acc0) * 2.0f;
    float off1 = tanhf(acc1) * 2.0f;
    float ix = fminf(fmaxf((float)px + off0, 0.f), 255.f);
    float iy = fminf(fmaxf((float)py + off1, 0.f), 255.f);
    float fx0 = floorf(ix), fy0 = floorf(iy);
    float wx = ix - fx0, wy = iy - fy0;
    int x0i = (int)fx0, y0i = (int)fy0;
    int x1i = min(x0i + 1, HW - 1), y1i = min(y0i + 1, HW - 1);
    float w00 = (1.f - wx) * (1.f - wy), w01 = wx * (1.f - wy);
    float w10 = (1.f - wx) * wy,         w11 = wx * wy;

    const int oA0 = y0i * HW + x0i, oA1 = y0i * HW + x1i;
    const int oB0 = y1i * HW + x0i, oB1 = y1i * HW + x1i;

    // ---- gather from global (L2-warm) + pack + swizzled NHWC store
    unsigned short* wb = warped + ((size_t)b * (HW * HW) + (size_t)py * HW + px) * CH;
    const int key = px & 7;
    #pragma unroll
    for (int j = 0; j < 8; ++j) {
        unsigned int pk[4];
        #pragma unroll
        for (int p = 0; p < 4; ++p) {
            unsigned int pw = 0;
            #pragma unroll
            for (int h = 0; h < 2; ++h) {
                int ci = j * 8 + p * 2 + h;
                const float* cp = xb + (size_t)ci * (HW * HW);
                float v = cp[oA0] * w00 + cp[oA1] * w01 +
                          cp[oB0] * w10 + cp[oB1] * w11;
                __hip_bfloat16 hh = __float2bfloat16(v);
                pw |= ((unsigned int)*(unsigned short*)&hh) << (16 * h);
            }
            pk[p] = pw;
        }
        uint4 q; q.x = pk[0]; q.y = pk[1]; q.z = pk[2]; q.w = pk[3];
        *(uint4*)&wb[(size_t)((j ^ key) * 8)] = q;
    }
}

// ---------------------------------------------------------------------------
// Kernel B: dilated(12) 3x3 conv 64->64 + BN + ReLU via bf16 MFMA implicit GEMM
// block = 256 threads (4 waves), computes 64co x 256px (one full output row).
// grid 2048 (XCD-chunked: XCD k = batch k -> oy,oy±12 rows reuse in its L2)
// ---------------------------------------------------------------------------
__global__ __launch_bounds__(256, 2) void conv_mfma_kernel(
    const unsigned short* __restrict__ warped, const unsigned short* __restrict__ wtb,
    const float* __restrict__ gamma, const float* __restrict__ beta,
    const float* __restrict__ mean, const float* __restrict__ var,
    float* __restrict__ out)
{
    __shared__ __align__(16) unsigned short sa[280 * 64];    // act row + 12px halos
    __shared__ __align__(16) unsigned short sw[3 * 64 * 64]; // weights for one ky
    __shared__ float sinv[64], sbias[64];

    const int t = threadIdx.x;
    const int orig = blockIdx.x;
    const int lid = (orig & 7) * 256 + (orig >> 3);
    const int oy = lid & 255, b = lid >> 8;
    const int wid = t >> 6, lane = t & 63;
    const int l15 = lane & 15, l4 = lane >> 4;

    if (t < 64) {
        float inv = gamma[t] * rsqrtf(var[t] + 1e-5f);
        sinv[t] = inv;
        sbias[t] = beta[t] - mean[t] * inv;
    }
    if (t < 192) {
        int p = t >> 3, sub = t & 7;
        int px = (p < 12) ? p : (256 + p);
        *(uint4*)&sa[px * 64 + sub * 8] = make_uint4(0, 0, 0, 0);
    }

    f32x4 acc[4][4];
    #pragma unroll
    for (int m = 0; m < 4; ++m)
        #pragma unroll
        for (int n = 0; n < 4; ++n) acc[m][n] = (f32x4){0.f, 0.f, 0.f, 0.f};

    const size_t bbase = (size_t)b * (HW * (size_t)HW * CH);

    for (int ky = 0; ky < 3; ++ky) {
        __syncthreads();
        int gy = oy + (ky - 1) * 12;
        if (gy >= 0 && gy < HW) {
            const char* src = (const char*)(warped + bbase + (size_t)gy * (HW * CH));
            #pragma unroll
            for (int r = 0; r < 8; ++r)
                gload16(src + r * 4096 + t * 16,
                        (char*)sa + 1536 + r * 4096 + wid * 1024);
        } else {
            #pragma unroll
            for (int r = 0; r < 8; ++r)
                *(uint4*)((char*)sa + 1536 + r * 4096 + t * 16) = make_uint4(0, 0, 0, 0);
        }
        {
            const char* wsrc = (const char*)wtb + ky * 24576;
            #pragma unroll
            for (int r = 0; r < 6; ++r)
                gload16(wsrc + r * 4096 + t * 16,
                        (char*)sw + r * 4096 + wid * 1024);
        }
        asm volatile("s_waitcnt vmcnt(0)" ::: "memory");
        __syncthreads();

        #pragma unroll
        for (int kx = 0; kx < 3; ++kx) {
            #pragma unroll
            for (int ks = 0; ks < 2; ++ks) {
                const int jg = ks * 4 + l4;
                bf16x8 af[4], bfr[4];
                #pragma unroll
                for (int m = 0; m < 4; ++m) {
                    int co = m * 16 + l15;
                    int jp = jg ^ (co & 7);
                    af[m] = *(const bf16x8*)&sw[(kx * 64 + co) * 64 + jp * 8];
                }
                #pragma unroll
                for (int n = 0; n < 4; ++n) {
                    int pl = wid * 64 + n * 16 + l15 + kx * 12;
                    int c = jg ^ ((pl + 4) & 7);
                    bfr[n] = *(const bf16x8*)&sa[pl * 64 + c * 8];
                }
                #pragma unroll
                for (int m = 0; m < 4; ++m)
                    #pragma unroll
                    for (int n = 0; n < 4; ++n)
                        acc[m][n] = __builtin_amdgcn_mfma_f32_16x16x32_bf16(
                            af[m], bfr[n], acc[m][n], 0, 0, 0);
            }
        }
    }

    #pragma unroll
    for (int m = 0; m < 4; ++m) {
        #pragma unroll
        for (int r = 0; r < 4; ++r) {
            int co = m * 16 + l4 * 4 + r;
            float inv = sinv[co], bs = sbias[co];
            float* orow = out + (((size_t)b * CH + co) * HW + oy) * HW + wid * 64 + l15;
            #pragma unroll
            for (int n = 0; n < 4; ++n)
                orow[n * 16] = fmaxf(fmaf(acc[m][n][r], inv, bs), 0.f);
        }
    }
}

extern "C" void kernel_launch(void* const* d_in, const int* in_sizes, int n_in,
                              void* d_out, int out_size, void* d_ws, size_t ws_size,
                              hipStream_t stream) {
    const float* x     = (const float*)d_in[0];
    const float* ow    = (const float*)d_in[1];
    const float* ob    = (const float*)d_in[2];
    const float* cw    = (const float*)d_in[3];
    const float* gamma = (const float*)d_in[4];
    const float* beta  = (const float*)d_in[5];
    const float* mean  = (const float*)d_in[6];
    const float* var   = (const float*)d_in[7];
    float* out = (float*)d_out;

    unsigned short* warped = (unsigned short*)d_ws;  // 64 MB NHWC bf16 (swizzled)
    unsigned short* wtb    = (unsigned short*)((char*)d_ws + (size_t)8 * CH * HW * HW * 2);

    wt_kernel<<<(9 * 64 * 64 + 255) / 256, 256, 0, stream>>>(cw, wtb);

    offset_warp_kernel<<<dim3(2048), 256, 0, stream>>>(x, ow, ob, warped);

    conv_mfma_kernel<<<dim3(2048), 256, 0, stream>>>(warped, wtb, gamma, beta, mean, var, out);
}

// Round 6
// 373.226 us; speedup vs baseline: 1.2297x; 1.2297x over previous
//
#include <hip/hip_runtime.h>
#include <hip/hip_bf16.h>
#include <cstdint>

#define HW 256
#define CH 64

typedef __attribute__((ext_vector_type(8))) short bf16x8;
typedef __attribute__((ext_vector_type(4))) float f32x4;

__device__ __forceinline__ float b2f(unsigned short u) {
    union { unsigned int i; float f; } c; c.i = ((unsigned int)u) << 16; return c.f;
}
__device__ __forceinline__ unsigned short f2b(float f) {
    __hip_bfloat16 h = __float2bfloat16(f);
    return *(unsigned short*)&h;
}
__device__ __forceinline__ void gload16(const void* g, void* l) {
    __builtin_amdgcn_global_load_lds(
        (const __attribute__((address_space(1))) void*)g,
        (__attribute__((address_space(3))) void*)l, 16, 0, 0);
}

// ---------------------------------------------------------------------------
// Kernel W: conv_w [co][ci][ky][kx] f32 -> wt[ky][kx][co][ci] bf16, with
// 16B-chunk XOR swizzle within each co-row: chunk j stored at j ^ (co&7).
// ---------------------------------------------------------------------------
__global__ void wt_kernel(const float* __restrict__ cw, unsigned short* __restrict__ wt) {
    int i = blockIdx.x * 256 + threadIdx.x;
    if (i >= 9 * 64 * 64) return;
    int e = i & 7, j = (i >> 3) & 7, co = (i >> 6) & 63, t9 = i >> 12;
    int ky = t9 / 3, kx = t9 - ky * 3;
    int ci = j * 8 + e;
    wt[t9 * 4096 + co * 64 + ((j ^ (co & 7)) * 8) + e] = f2b(cw[co * 576 + ci * 9 + ky * 3 + kx]);
}

// ---------------------------------------------------------------------------
// Kernel A1: offset conv (fp32-exact) -> offs [b][py][px][2] interleaved f32.
// 32x32 tile, 4px/thread (1x4), 4-ci groups x16, double-buffered LDS
// [4][34 rows][40 floats] (stride 40 -> b128-aligned taps), T14 issue/commit.
// grid 512, block 256.
// ---------------------------------------------------------------------------
__global__ __launch_bounds__(256) void offset_conv_kernel(
    const float* __restrict__ x, const float* __restrict__ ow,
    const float* __restrict__ ob, float* __restrict__ offs)
{
    __shared__ __align__(16) float sg[2][4 * 34 * 40];   // 2 x 21760 B

    const int lid = blockIdx.x;
    const int bx = lid & 7, by = (lid >> 3) & 7, b = lid >> 6;
    const int t = threadIdx.x;
    const int i = t & 7, r = t >> 3;            // x-quad in [0,8), row in [0,32)
    const int x0 = bx * 32, y0 = by * 32;
    const float* xb = x + (size_t)b * CH * HW * HW;

    float rv[10][2];
    auto issue = [&](int g) {
        #pragma unroll
        for (int k = 0; k < 10; ++k) {
            int idx = k * 256 + t;
            rv[k][0] = 0.f; rv[k][1] = 0.f;
            if (idx < 2448) {
                int ci4 = idx / 612;
                int rem = idx - ci4 * 612;
                int ly  = rem / 18, k2 = rem - ly * 18;
                int gy = y0 - 1 + ly, gx = x0 - 2 + 2 * k2;   // gx even
                bool ok = ((unsigned)gy < 256u) && ((unsigned)gx < 256u);
                int cy = min(max(gy, 0), 255), cx = min(max(gx, 0), 254);
                float2 v = *(const float2*)&xb[((size_t)(g * 4 + ci4) * HW + cy) * HW + cx];
                if (ok) { rv[k][0] = v.x; rv[k][1] = v.y; }
            }
        }
    };
    auto commit = [&](float* buf) {
        #pragma unroll
        for (int k = 0; k < 10; ++k) {
            int idx = k * 256 + t;
            if (idx < 2448) {
                int ci4 = idx / 612;
                int rem = idx - ci4 * 612;
                int ly  = rem / 18, k2 = rem - ly * 18;
                *(float2*)&buf[ci4 * 1360 + ly * 40 + 2 * k2] = make_float2(rv[k][0], rv[k][1]);
            }
        }
    };

    issue(0); commit(sg[0]);
    __syncthreads();

    float a0[4], a1[4];
    #pragma unroll
    for (int j = 0; j < 4; ++j) { a0[j] = ob[0]; a1[j] = ob[1]; }

    for (int g = 0; g < 16; ++g) {
        if (g < 15) issue(g + 1);
        const float* buf = sg[g & 1];
        #pragma unroll
        for (int ci4 = 0; ci4 < 4; ++ci4) {
            int ci = g * 4 + ci4;
            const float* w0 = &ow[ci * 9];          // wave-uniform -> s_load
            const float* w1 = &ow[(CH + ci) * 9];
            const float* pb = buf + ci4 * 1360 + 4 * i;
            #pragma unroll
            for (int ky = 0; ky < 3; ++ky) {
                const float4 qa = *(const float4*)(pb + (r + ky) * 40);
                const float4 qb = *(const float4*)(pb + (r + ky) * 40 + 4);
                float tv[8] = {qa.x, qa.y, qa.z, qa.w, qb.x, qb.y, qb.z, qb.w};
                #pragma unroll
                for (int kx = 0; kx < 3; ++kx) {
                    float wa = w0[ky * 3 + kx], wbv = w1[ky * 3 + kx];
                    #pragma unroll
                    for (int j = 0; j < 4; ++j) {
                        a0[j] = fmaf(tv[j + kx + 1], wa, a0[j]);
                        a1[j] = fmaf(tv[j + kx + 1], wbv, a1[j]);
                    }
                }
            }
        }
        if (g < 15) { commit(sg[(g + 1) & 1]); __syncthreads(); }
    }

    const int py = y0 + r, px0 = x0 + 4 * i;
    float o[8];
    #pragma unroll
    for (int j = 0; j < 4; ++j) {
        o[2 * j]     = tanhf(a0[j]) * 2.0f;
        o[2 * j + 1] = tanhf(a1[j]) * 2.0f;
    }
    float* op = offs + (((size_t)b * HW + py) * HW + px0) * 2;
    *(float4*)op       = make_float4(o[0], o[1], o[2], o[3]);
    *(float4*)(op + 4) = make_float4(o[4], o[5], o[6], o[7]);
}

// ---------------------------------------------------------------------------
// Kernel A2: bilinear warp from LDS tiles. 16x16 tile, 1 px/thread.
// |offset|<2 => all taps in [x0-2,x0+18) x [y0-2,y0+18). bf16 tile
// [8ci][20 rows][11 words] double-buffered = 14 KB. 8 ci-groups, T14 split.
// Output accumulated in 8 uint4 regs -> one 128B contiguous store per px.
// Output: warped bf16 NHWC [b][y][x][ci], 16B chunk j stored at j^(px&7).
// grid 2048, block 256.
// ---------------------------------------------------------------------------
__global__ __launch_bounds__(256, 4) void warp_kernel(
    const float* __restrict__ x, const float* __restrict__ offs,
    unsigned short* __restrict__ warped)
{
    __shared__ __align__(16) unsigned int sx[2][8 * 20 * 11];   // 2 x 7040 B

    const int lid = blockIdx.x;
    const int bx = lid & 15, by = (lid >> 4) & 15, b = lid >> 8;
    const int t = threadIdx.x;
    const int tx = t & 15, ty = t >> 4;
    const int x0 = bx * 16, y0 = by * 16;
    const int px = x0 + tx, py = y0 + ty;
    const float* xb = x + (size_t)b * CH * HW * HW;

    float rv[7][2];
    auto issue = [&](int g) {
        #pragma unroll
        for (int k = 0; k < 7; ++k) {
            int idx = k * 256 + t;
            rv[k][0] = 0.f; rv[k][1] = 0.f;
            if (idx < 1600) {
                int ci8 = idx / 200;
                int rem = idx - ci8 * 200;
                int ly = rem / 10, k2 = rem - ly * 10;
                int gy = y0 - 2 + ly, gx = x0 - 2 + 2 * k2;   // gx even
                bool ok = ((unsigned)gy < 256u) && ((unsigned)gx < 256u);
                int cy = min(max(gy, 0), 255), cx = min(max(gx, 0), 254);
                float2 v = *(const float2*)&xb[((size_t)(g * 8 + ci8) * HW + cy) * HW + cx];
                if (ok) { rv[k][0] = v.x; rv[k][1] = v.y; }
            }
        }
    };
    auto commit = [&](unsigned int* buf) {
        #pragma unroll
        for (int k = 0; k < 7; ++k) {
            int idx = k * 256 + t;
            if (idx < 1600) {
                int ci8 = idx / 200;
                int rem = idx - ci8 * 200;
                int ly = rem / 10, k2 = rem - ly * 10;
                buf[ci8 * 220 + ly * 11 + k2] =
                    (unsigned int)f2b(rv[k][0]) | ((unsigned int)f2b(rv[k][1]) << 16);
            }
        }
    };

    // per-px tap setup (fp32-exact offsets)
    const float2 off = *(const float2*)&offs[(((size_t)b * HW + py) * HW + px) * 2];
    float ix = fminf(fmaxf((float)px + off.x, 0.f), 255.f);
    float iy = fminf(fmaxf((float)py + off.y, 0.f), 255.f);
    float fx0 = floorf(ix), fy0 = floorf(iy);
    float wx = ix - fx0, wy = iy - fy0;
    int lx0 = (int)fx0 - x0 + 2;    // in [0,18]
    int ly0 = (int)fy0 - y0 + 2;    // in [0,18]
    float w00 = (1.f - wx) * (1.f - wy), w01 = wx * (1.f - wy);
    float w10 = (1.f - wx) * wy,         w11 = wx * wy;
    // x1i!=x0i+1 only at ix==255 where wx==0 (weight 0); same for y. In-tile
    // next-short / next-row reads are staged (zero-padded) -> correct.
    const int wbase = ly0 * 11 + (lx0 >> 1);
    const int sh = (lx0 & 1) * 16;

    issue(0); commit(sx[0]);
    __syncthreads();

    uint4 pk[8];
    #pragma unroll
    for (int g = 0; g < 8; ++g) {
        if (g < 7) issue(g + 1);
        const unsigned int* S = sx[g & 1];
        unsigned int res[4];
        #pragma unroll
        for (int p = 0; p < 4; ++p) {
            unsigned int pw = 0;
            #pragma unroll
            for (int h = 0; h < 2; ++h) {
                int base = (p * 2 + h) * 220 + wbase;
                unsigned long long ra =
                    ((unsigned long long)S[base + 1] << 32) | (unsigned long long)S[base];
                ra >>= sh;
                unsigned long long rb =
                    ((unsigned long long)S[base + 12] << 32) | (unsigned long long)S[base + 11];
                rb >>= sh;
                float v = b2f((unsigned short)ra) * w00 +
                          b2f((unsigned short)(ra >> 16)) * w01 +
                          b2f((unsigned short)rb) * w10 +
                          b2f((unsigned short)(rb >> 16)) * w11;
                pw |= ((unsigned int)f2b(v)) << (16 * h);
            }
            res[p] = pw;
        }
        pk[g] = make_uint4(res[0], res[1], res[2], res[3]);
        if (g < 7) { commit(sx[(g + 1) & 1]); __syncthreads(); }
    }

    unsigned short* wbp = warped + ((size_t)b * (HW * HW) + (size_t)py * HW + px) * CH;
    const int key = px & 7;
    #pragma unroll
    for (int g = 0; g < 8; ++g)
        *(uint4*)&wbp[(size_t)((g ^ key) * 8)] = pk[g];
}

// ---------------------------------------------------------------------------
// Kernel B: dilated(12) 3x3 conv 64->64 + BN + ReLU via bf16 MFMA implicit GEMM
// block = 256 threads (4 waves), computes 64co x 256px (one full output row).
// grid 2048 (XCD-chunked: XCD k = batch k -> oy,oy±12 rows reuse in its L2)
// ---------------------------------------------------------------------------
__global__ __launch_bounds__(256, 2) void conv_mfma_kernel(
    const unsigned short* __restrict__ warped, const unsigned short* __restrict__ wtb,
    const float* __restrict__ gamma, const float* __restrict__ beta,
    const float* __restrict__ mean, const float* __restrict__ var,
    float* __restrict__ out)
{
    __shared__ __align__(16) unsigned short sa[280 * 64];    // act row + 12px halos
    __shared__ __align__(16) unsigned short sw[3 * 64 * 64]; // weights for one ky
    __shared__ float sinv[64], sbias[64];

    const int t = threadIdx.x;
    const int orig = blockIdx.x;
    const int lid = (orig & 7) * 256 + (orig >> 3);
    const int oy = lid & 255, b = lid >> 8;
    const int wid = t >> 6, lane = t & 63;
    const int l15 = lane & 15, l4 = lane >> 4;

    if (t < 64) {
        float inv = gamma[t] * rsqrtf(var[t] + 1e-5f);
        sinv[t] = inv;
        sbias[t] = beta[t] - mean[t] * inv;
    }
    if (t < 192) {
        int p = t >> 3, sub = t & 7;
        int px = (p < 12) ? p : (256 + p);
        *(uint4*)&sa[px * 64 + sub * 8] = make_uint4(0, 0, 0, 0);
    }

    f32x4 acc[4][4];
    #pragma unroll
    for (int m = 0; m < 4; ++m)
        #pragma unroll
        for (int n = 0; n < 4; ++n) acc[m][n] = (f32x4){0.f, 0.f, 0.f, 0.f};

    const size_t bbase = (size_t)b * (HW * (size_t)HW * CH);

    for (int ky = 0; ky < 3; ++ky) {
        __syncthreads();
        int gy = oy + (ky - 1) * 12;
        if (gy >= 0 && gy < HW) {
            const char* src = (const char*)(warped + bbase + (size_t)gy * (HW * CH));
            #pragma unroll
            for (int r = 0; r < 8; ++r)
                gload16(src + r * 4096 + t * 16,
                        (char*)sa + 1536 + r * 4096 + wid * 1024);
        } else {
            #pragma unroll
            for (int r = 0; r < 8; ++r)
                *(uint4*)((char*)sa + 1536 + r * 4096 + t * 16) = make_uint4(0, 0, 0, 0);
        }
        {
            const char* wsrc = (const char*)wtb + ky * 24576;
            #pragma unroll
            for (int r = 0; r < 6; ++r)
                gload16(wsrc + r * 4096 + t * 16,
                        (char*)sw + r * 4096 + wid * 1024);
        }
        asm volatile("s_waitcnt vmcnt(0)" ::: "memory");
        __syncthreads();

        #pragma unroll
        for (int kx = 0; kx < 3; ++kx) {
            #pragma unroll
            for (int ks = 0; ks < 2; ++ks) {
                const int jg = ks * 4 + l4;
                bf16x8 af[4], bfr[4];
                #pragma unroll
                for (int m = 0; m < 4; ++m) {
                    int co = m * 16 + l15;
                    int jp = jg ^ (co & 7);
                    af[m] = *(const bf16x8*)&sw[(kx * 64 + co) * 64 + jp * 8];
                }
                #pragma unroll
                for (int n = 0; n < 4; ++n) {
                    int pl = wid * 64 + n * 16 + l15 + kx * 12;
                    int c = jg ^ ((pl + 4) & 7);
                    bfr[n] = *(const bf16x8*)&sa[pl * 64 + c * 8];
                }
                #pragma unroll
                for (int m = 0; m < 4; ++m)
                    #pragma unroll
                    for (int n = 0; n < 4; ++n)
                        acc[m][n] = __builtin_amdgcn_mfma_f32_16x16x32_bf16(
                            af[m], bfr[n], acc[m][n], 0, 0, 0);
            }
        }
    }

    #pragma unroll
    for (int m = 0; m < 4; ++m) {
        #pragma unroll
        for (int r = 0; r < 4; ++r) {
            int co = m * 16 + l4 * 4 + r;
            float inv = sinv[co], bs = sbias[co];
            float* orow = out + (((size_t)b * CH + co) * HW + oy) * HW + wid * 64 + l15;
            #pragma unroll
            for (int n = 0; n < 4; ++n)
                orow[n * 16] = fmaxf(fmaf(acc[m][n][r], inv, bs), 0.f);
        }
    }
}

extern "C" void kernel_launch(void* const* d_in, const int* in_sizes, int n_in,
                              void* d_out, int out_size, void* d_ws, size_t ws_size,
                              hipStream_t stream) {
    const float* x     = (const float*)d_in[0];
    const float* ow    = (const float*)d_in[1];
    const float* ob    = (const float*)d_in[2];
    const float* cw    = (const float*)d_in[3];
    const float* gamma = (const float*)d_in[4];
    const float* beta  = (const float*)d_in[5];
    const float* mean  = (const float*)d_in[6];
    const float* var   = (const float*)d_in[7];
    float* out = (float*)d_out;

    unsigned short* warped = (unsigned short*)d_ws;                       // 64 MB
    unsigned short* wtb    = (unsigned short*)((char*)d_ws + 67108864);   // 72 KB
    float*          offsb  = (float*)((char*)d_ws + 67108864 + 73728);    // 4.2 MB

    wt_kernel<<<(9 * 64 * 64 + 255) / 256, 256, 0, stream>>>(cw, wtb);

    offset_conv_kernel<<<dim3(512), 256, 0, stream>>>(x, ow, ob, offsb);

    warp_kernel<<<dim3(2048), 256, 0, stream>>>(x, offsb, warped);

    conv_mfma_kernel<<<dim3(2048), 256, 0, stream>>>(warped, wtb, gamma, beta, mean, var, out);
}

// Round 7
// 273.029 us; speedup vs baseline: 1.6810x; 1.3670x over previous
//
#include <hip/hip_runtime.h>
#include <hip/hip_bf16.h>
#include <cstdint>

#define HW 256
#define CH 64

typedef __attribute__((ext_vector_type(8))) short bf16x8;
typedef __attribute__((ext_vector_type(4))) float f32x4;

__device__ __forceinline__ float b2f(unsigned short u) {
    union { unsigned int i; float f; } c; c.i = ((unsigned int)u) << 16; return c.f;
}
__device__ __forceinline__ unsigned short f2b(float f) {
    __hip_bfloat16 h = __float2bfloat16(f);
    return *(unsigned short*)&h;
}
__device__ __forceinline__ void gload16(const void* g, void* l) {
    __builtin_amdgcn_global_load_lds(
        (const __attribute__((address_space(1))) void*)g,
        (__attribute__((address_space(3))) void*)l, 16, 0, 0);
}

// ---------------------------------------------------------------------------
// Kernel W: conv_w [co][ci][ky][kx] f32 -> wt[ky][kx][co][ci] bf16, with
// 16B-chunk XOR swizzle within each co-row: chunk j stored at j ^ (co&7).
// ---------------------------------------------------------------------------
__global__ void wt_kernel(const float* __restrict__ cw, unsigned short* __restrict__ wt) {
    int i = blockIdx.x * 256 + threadIdx.x;
    if (i >= 9 * 64 * 64) return;
    int e = i & 7, j = (i >> 3) & 7, co = (i >> 6) & 63, t9 = i >> 12;
    int ky = t9 / 3, kx = t9 - ky * 3;
    int ci = j * 8 + e;
    wt[t9 * 4096 + co * 64 + ((j ^ (co & 7)) * 8) + e] = f2b(cw[co * 576 + ci * 9 + ky * 3 + kx]);
}

// ---------------------------------------------------------------------------
// Kernel A1: offset conv (fp32-exact) -> offs [b][py][px][2] interleaved f32.
// 32x32 tile, 4px/thread, 4-ci groups x16, double-buffered LDS, T14 split.
// grid 512 (XCD-chunked: one image per XCD), block 256.
// ---------------------------------------------------------------------------
__global__ __launch_bounds__(256) void offset_conv_kernel(
    const float* __restrict__ x, const float* __restrict__ ow,
    const float* __restrict__ ob, float* __restrict__ offs)
{
    __shared__ __align__(16) float sg[2][4 * 34 * 40];   // 2 x 21760 B

    const int orig = blockIdx.x;
    const int lid = (orig & 7) * 64 + (orig >> 3);       // XCD k owns image k
    const int bx = lid & 7, by = (lid >> 3) & 7, b = lid >> 6;
    const int t = threadIdx.x;
    const int i = t & 7, r = t >> 3;            // x-quad in [0,8), row in [0,32)
    const int x0 = bx * 32, y0 = by * 32;
    const float* xb = x + (size_t)b * CH * HW * HW;

    float rv[10][2];
    auto issue = [&](int g) {
        #pragma unroll
        for (int k = 0; k < 10; ++k) {
            int idx = k * 256 + t;
            rv[k][0] = 0.f; rv[k][1] = 0.f;
            if (idx < 2448) {
                int ci4 = idx / 612;
                int rem = idx - ci4 * 612;
                int ly  = rem / 18, k2 = rem - ly * 18;
                int gy = y0 - 1 + ly, gx = x0 - 2 + 2 * k2;   // gx even
                bool ok = ((unsigned)gy < 256u) && ((unsigned)gx < 256u);
                int cy = min(max(gy, 0), 255), cx = min(max(gx, 0), 254);
                float2 v = *(const float2*)&xb[((size_t)(g * 4 + ci4) * HW + cy) * HW + cx];
                if (ok) { rv[k][0] = v.x; rv[k][1] = v.y; }
            }
        }
    };
    auto commit = [&](float* buf) {
        #pragma unroll
        for (int k = 0; k < 10; ++k) {
            int idx = k * 256 + t;
            if (idx < 2448) {
                int ci4 = idx / 612;
                int rem = idx - ci4 * 612;
                int ly  = rem / 18, k2 = rem - ly * 18;
                *(float2*)&buf[ci4 * 1360 + ly * 40 + 2 * k2] = make_float2(rv[k][0], rv[k][1]);
            }
        }
    };

    issue(0); commit(sg[0]);
    __syncthreads();

    float a0[4], a1[4];
    #pragma unroll
    for (int j = 0; j < 4; ++j) { a0[j] = ob[0]; a1[j] = ob[1]; }

    for (int g = 0; g < 16; ++g) {
        if (g < 15) issue(g + 1);
        const float* buf = sg[g & 1];
        #pragma unroll
        for (int ci4 = 0; ci4 < 4; ++ci4) {
            int ci = g * 4 + ci4;
            const float* w0 = &ow[ci * 9];          // wave-uniform -> s_load
            const float* w1 = &ow[(CH + ci) * 9];
            const float* pb = buf + ci4 * 1360 + 4 * i;
            #pragma unroll
            for (int ky = 0; ky < 3; ++ky) {
                const float4 qa = *(const float4*)(pb + (r + ky) * 40);
                const float4 qb = *(const float4*)(pb + (r + ky) * 40 + 4);
                float tv[8] = {qa.x, qa.y, qa.z, qa.w, qb.x, qb.y, qb.z, qb.w};
                #pragma unroll
                for (int kx = 0; kx < 3; ++kx) {
                    float wa = w0[ky * 3 + kx], wbv = w1[ky * 3 + kx];
                    #pragma unroll
                    for (int j = 0; j < 4; ++j) {
                        a0[j] = fmaf(tv[j + kx + 1], wa, a0[j]);
                        a1[j] = fmaf(tv[j + kx + 1], wbv, a1[j]);
                    }
                }
            }
        }
        if (g < 15) { commit(sg[(g + 1) & 1]); __syncthreads(); }
    }

    const int py = y0 + r, px0 = x0 + 4 * i;
    float o[8];
    #pragma unroll
    for (int j = 0; j < 4; ++j) {
        o[2 * j]     = tanhf(a0[j]) * 2.0f;
        o[2 * j + 1] = tanhf(a1[j]) * 2.0f;
    }
    float* op = offs + (((size_t)b * HW + py) * HW + px0) * 2;
    *(float4*)op       = make_float4(o[0], o[1], o[2], o[3]);
    *(float4*)(op + 4) = make_float4(o[4], o[5], o[6], o[7]);
}

// ---------------------------------------------------------------------------
// Kernel A2: bilinear warp from LDS tiles. 32x32 tile, 4 px/thread.
// |offset|<2 => taps in [x0-2,x0+34) x [y0-2,y0+34). bf16 tile
// [8ci][36 rows][19 words] double-buffered = 43.8 KB -> 3 blk/CU.
// 8 ci-groups, T14 issue/commit, per-group direct 16B swizzled-chunk stores
// (L2 write-combines the 8 chunks per 128B px line).
// grid 512 (XCD-chunked: one image per XCD), block 256.
// Output: warped bf16 NHWC [b][y][x][ci], 16B chunk j stored at j^(px&7).
// ---------------------------------------------------------------------------
__global__ __launch_bounds__(256, 3) void warp_kernel(
    const float* __restrict__ x, const float* __restrict__ offs,
    unsigned short* __restrict__ warped)
{
    __shared__ __align__(16) unsigned int sx[2][8 * 36 * 19];   // 2 x 21888 B

    const int orig = blockIdx.x;
    const int lid = (orig & 7) * 64 + (orig >> 3);       // XCD k owns image k
    const int tile = lid & 63, b = lid >> 6;
    const int bx = tile & 7, by = tile >> 3;
    const int x0 = bx * 32, y0 = by * 32;
    const int t = threadIdx.x;
    const int i = t & 7, r = t >> 3;                     // x-oct, row
    const int px0 = x0 + 4 * i, py = y0 + r;
    const float* xb = x + (size_t)b * CH * HW * HW;

    // zero the never-staged pad word 18 of each row (both buffers), once
    for (int idx = t; idx < 576; idx += 256) {
        int bi = idx >= 288, rem2 = idx - bi * 288;
        int ci8 = rem2 / 36, ly = rem2 - ci8 * 36;
        sx[bi][ci8 * 684 + ly * 19 + 18] = 0;
    }

    // ---- per-px tap setup (fp32-exact offsets)
    const float4 of01 = *(const float4*)&offs[(((size_t)b * HW + py) * HW + px0) * 2];
    const float4 of23 = *(const float4*)&offs[(((size_t)b * HW + py) * HW + px0) * 2 + 4];
    const float offx[4] = {of01.x, of01.z, of23.x, of23.z};
    const float offy[4] = {of01.y, of01.w, of23.y, of23.w};
    int wbase[4], shs[4];
    float w00[4], w01[4], w10[4], w11[4];
    #pragma unroll
    for (int j = 0; j < 4; ++j) {
        int px = px0 + j;
        float ix = fminf(fmaxf((float)px + offx[j], 0.f), 255.f);
        float iy = fminf(fmaxf((float)py + offy[j], 0.f), 255.f);
        float fx0 = floorf(ix), fy0 = floorf(iy);
        float wx = ix - fx0, wy = iy - fy0;
        int lx0 = (int)fx0 - x0 + 2;   // in [2,35]
        int ly0 = (int)fy0 - y0 + 2;   // in [2,34]
        w00[j] = (1.f - wx) * (1.f - wy); w01[j] = wx * (1.f - wy);
        w10[j] = (1.f - wx) * wy;         w11[j] = wx * wy;
        wbase[j] = ly0 * 19 + (lx0 >> 1);
        shs[j] = (lx0 & 1) * 16;
    }

    float rv[21][2];
    auto issue = [&](int g) {
        #pragma unroll
        for (int k = 0; k < 21; ++k) {
            int idx = k * 256 + t;
            rv[k][0] = 0.f; rv[k][1] = 0.f;
            if (idx < 5184) {
                int ci8 = idx / 648;
                int rem = idx - ci8 * 648;
                int ly = rem / 18, k2 = rem - ly * 18;
                int gy = y0 - 2 + ly, gx = x0 - 2 + 2 * k2;   // gx even
                bool ok = ((unsigned)gy < 256u) && ((unsigned)gx < 256u);
                int cy = min(max(gy, 0), 255), cx = min(max(gx, 0), 254);
                float2 v = *(const float2*)&xb[((size_t)(g * 8 + ci8) * HW + cy) * HW + cx];
                if (ok) { rv[k][0] = v.x; rv[k][1] = v.y; }
            }
        }
    };
    auto commit = [&](unsigned int* buf) {
        #pragma unroll
        for (int k = 0; k < 21; ++k) {
            int idx = k * 256 + t;
            if (idx < 5184) {
                int ci8 = idx / 648;
                int rem = idx - ci8 * 648;
                int ly = rem / 18, k2 = rem - ly * 18;
                buf[ci8 * 684 + ly * 19 + k2] =
                    (unsigned int)f2b(rv[k][0]) | ((unsigned int)f2b(rv[k][1]) << 16);
            }
        }
    };

    issue(0); commit(sx[0]);
    __syncthreads();

    unsigned short* wb0 = warped + ((size_t)b * (HW * HW) + (size_t)py * HW + px0) * CH;
    for (int g = 0; g < 8; ++g) {
        if (g < 7) issue(g + 1);
        const unsigned int* S = sx[g & 1];
        #pragma unroll
        for (int j = 0; j < 4; ++j) {
            unsigned int res[4];
            #pragma unroll
            for (int p = 0; p < 4; ++p) {
                unsigned int pw = 0;
                #pragma unroll
                for (int h = 0; h < 2; ++h) {
                    int base = (p * 2 + h) * 684 + wbase[j];
                    unsigned long long ra =
                        ((unsigned long long)S[base + 1] << 32) | (unsigned long long)S[base];
                    ra >>= shs[j];
                    unsigned long long rb =
                        ((unsigned long long)S[base + 20] << 32) | (unsigned long long)S[base + 19];
                    rb >>= shs[j];
                    float v = b2f((unsigned short)ra) * w00[j] +
                              b2f((unsigned short)(ra >> 16)) * w01[j] +
                              b2f((unsigned short)rb) * w10[j] +
                              b2f((unsigned short)(rb >> 16)) * w11[j];
                    pw |= ((unsigned int)f2b(v)) << (16 * h);
                }
                res[p] = pw;
            }
            const int key = (px0 + j) & 7;
            *(uint4*)&wb0[(size_t)j * CH + (size_t)((g ^ key) * 8)] =
                make_uint4(res[0], res[1], res[2], res[3]);
        }
        if (g < 7) { commit(sx[(g + 1) & 1]); __syncthreads(); }
    }
}

// ---------------------------------------------------------------------------
// Kernel B: dilated(12) 3x3 conv 64->64 + BN + ReLU via bf16 MFMA implicit GEMM
// block = 256 threads (4 waves), computes 64co x 256px (one full output row).
// grid 2048 (XCD-chunked: XCD k = batch k -> oy,oy±12 rows reuse in its L2)
// ---------------------------------------------------------------------------
__global__ __launch_bounds__(256, 2) void conv_mfma_kernel(
    const unsigned short* __restrict__ warped, const unsigned short* __restrict__ wtb,
    const float* __restrict__ gamma, const float* __restrict__ beta,
    const float* __restrict__ mean, const float* __restrict__ var,
    float* __restrict__ out)
{
    __shared__ __align__(16) unsigned short sa[280 * 64];    // act row + 12px halos
    __shared__ __align__(16) unsigned short sw[3 * 64 * 64]; // weights for one ky
    __shared__ float sinv[64], sbias[64];

    const int t = threadIdx.x;
    const int orig = blockIdx.x;
    const int lid = (orig & 7) * 256 + (orig >> 3);
    const int oy = lid & 255, b = lid >> 8;
    const int wid = t >> 6, lane = t & 63;
    const int l15 = lane & 15, l4 = lane >> 4;

    if (t < 64) {
        float inv = gamma[t] * rsqrtf(var[t] + 1e-5f);
        sinv[t] = inv;
        sbias[t] = beta[t] - mean[t] * inv;
    }
    if (t < 192) {
        int p = t >> 3, sub = t & 7;
        int px = (p < 12) ? p : (256 + p);
        *(uint4*)&sa[px * 64 + sub * 8] = make_uint4(0, 0, 0, 0);
    }

    f32x4 acc[4][4];
    #pragma unroll
    for (int m = 0; m < 4; ++m)
        #pragma unroll
        for (int n = 0; n < 4; ++n) acc[m][n] = (f32x4){0.f, 0.f, 0.f, 0.f};

    const size_t bbase = (size_t)b * (HW * (size_t)HW * CH);

    for (int ky = 0; ky < 3; ++ky) {
        __syncthreads();
        int gy = oy + (ky - 1) * 12;
        if (gy >= 0 && gy < HW) {
            const char* src = (const char*)(warped + bbase + (size_t)gy * (HW * CH));
            #pragma unroll
            for (int r = 0; r < 8; ++r)
                gload16(src + r * 4096 + t * 16,
                        (char*)sa + 1536 + r * 4096 + wid * 1024);
        } else {
            #pragma unroll
            for (int r = 0; r < 8; ++r)
                *(uint4*)((char*)sa + 1536 + r * 4096 + t * 16) = make_uint4(0, 0, 0, 0);
        }
        {
            const char* wsrc = (const char*)wtb + ky * 24576;
            #pragma unroll
            for (int r = 0; r < 6; ++r)
                gload16(wsrc + r * 4096 + t * 16,
                        (char*)sw + r * 4096 + wid * 1024);
        }
        asm volatile("s_waitcnt vmcnt(0)" ::: "memory");
        __syncthreads();

        #pragma unroll
        for (int kx = 0; kx < 3; ++kx) {
            #pragma unroll
            for (int ks = 0; ks < 2; ++ks) {
                const int jg = ks * 4 + l4;
                bf16x8 af[4], bfr[4];
                #pragma unroll
                for (int m = 0; m < 4; ++m) {
                    int co = m * 16 + l15;
                    int jp = jg ^ (co & 7);
                    af[m] = *(const bf16x8*)&sw[(kx * 64 + co) * 64 + jp * 8];
                }
                #pragma unroll
                for (int n = 0; n < 4; ++n) {
                    int pl = wid * 64 + n * 16 + l15 + kx * 12;
                    int c = jg ^ ((pl + 4) & 7);
                    bfr[n] = *(const bf16x8*)&sa[pl * 64 + c * 8];
                }
                #pragma unroll
                for (int m = 0; m < 4; ++m)
                    #pragma unroll
                    for (int n = 0; n < 4; ++n)
                        acc[m][n] = __builtin_amdgcn_mfma_f32_16x16x32_bf16(
                            af[m], bfr[n], acc[m][n], 0, 0, 0);
            }
        }
    }

    #pragma unroll
    for (int m = 0; m < 4; ++m) {
        #pragma unroll
        for (int r = 0; r < 4; ++r) {
            int co = m * 16 + l4 * 4 + r;
            float inv = sinv[co], bs = sbias[co];
            float* orow = out + (((size_t)b * CH + co) * HW + oy) * HW + wid * 64 + l15;
            #pragma unroll
            for (int n = 0; n < 4; ++n)
                orow[n * 16] = fmaxf(fmaf(acc[m][n][r], inv, bs), 0.f);
        }
    }
}

extern "C" void kernel_launch(void* const* d_in, const int* in_sizes, int n_in,
                              void* d_out, int out_size, void* d_ws, size_t ws_size,
                              hipStream_t stream) {
    const float* x     = (const float*)d_in[0];
    const float* ow    = (const float*)d_in[1];
    const float* ob    = (const float*)d_in[2];
    const float* cw    = (const float*)d_in[3];
    const float* gamma = (const float*)d_in[4];
    const float* beta  = (const float*)d_in[5];
    const float* mean  = (const float*)d_in[6];
    const float* var   = (const float*)d_in[7];
    float* out = (float*)d_out;

    unsigned short* warped = (unsigned short*)d_ws;                       // 64 MB
    unsigned short* wtb    = (unsigned short*)((char*)d_ws + 67108864);   // 72 KB
    float*          offsb  = (float*)((char*)d_ws + 67108864 + 73728);    // 4.2 MB

    wt_kernel<<<(9 * 64 * 64 + 255) / 256, 256, 0, stream>>>(cw, wtb);

    offset_conv_kernel<<<dim3(512), 256, 0, stream>>>(x, ow, ob, offsb);

    warp_kernel<<<dim3(512), 256, 0, stream>>>(x, offsb, warped);

    conv_mfma_kernel<<<dim3(2048), 256, 0, stream>>>(warped, wtb, gamma, beta, mean, var, out);
}